// Round 1
// baseline (372.804 us; speedup 1.0000x reference)
//
#include <hip/hip_runtime.h>
#include <math.h>

#define N_IMG 64
#define H_IMG 512
#define W_IMG 512
#define EPSF 1e-6f

// acc layout in d_ws (floats):
// [0] = bce_sum (sum of selected logs)
// [1] = fd |S0-S1| sum     [2] = fd count(S1>0)
// [3..66]   = dsum64 (8x8 grid, row-major), |sigmoid(p)-g| summed over batch+patch
// [67..130] = cnt64  (8x8 grid), count(g>0) summed over batch+patch
#define ACC_FLOATS 131

__device__ __forceinline__ float wave_reduce_add(float v) {
#pragma unroll
    for (int off = 32; off > 0; off >>= 1)
        v += __shfl_down(v, off, 64);
    return v;  // valid in lane 0
}

__global__ __launch_bounds__(256) void loss_main(
    const float* __restrict__ pred, const float* __restrict__ gt,
    float* __restrict__ acc)
{
    __shared__ float l_s0a[256], l_s0b[256], l_s1a[256], l_s1b[256];
    __shared__ float l_pd[32], l_pc[32], l_bce[4];

    const int b   = blockIdx.x;
    const int n   = b >> 7;        // image
    const int rg  = b & 127;       // 4-row group within image
    const int tid = threadIdx.x;
    const int r   = tid >> 6;      // row within group, 0..3 (one wave per row)
    const int c   = tid & 63;      // col chunk, 8 floats each
    const int row = rg * 4 + r;
    const size_t base = ((size_t)(n * H_IMG + row)) * W_IMG + (size_t)(c * 8);

    const float4 p0 = *(const float4*)(pred + base);
    const float4 p1 = *(const float4*)(pred + base + 4);
    const float4 g0 = *(const float4*)(gt + base);
    const float4 g1 = *(const float4*)(gt + base + 4);

    const float pv[8] = {p0.x,p0.y,p0.z,p0.w,p1.x,p1.y,p1.z,p1.w};
    const float gv[8] = {g0.x,g0.y,g0.z,g0.w,g1.x,g1.y,g1.z,g1.w};

    float bce = 0.f, dsum = 0.f, cnt = 0.f;
    float s0a = 0.f, s0b = 0.f, s1a = 0.f, s1b = 0.f;
#pragma unroll
    for (int i = 0; i < 8; ++i) {
        const float p = pv[i], g = gv[i];
        const float sig = __builtin_amdgcn_rcpf(1.0f + __expf(-p));
        // gt is exactly 0/1: g*log(p)+(1-g)*log(1-p) == log(g>0.5 ? p : 1-p)
        bce  += __logf(g > 0.5f ? p : 1.0f - p);
        dsum += fabsf(sig - g);
        cnt  += (g > 0.f) ? 1.f : 0.f;
        if (i < 4) { s0a += sig; s1a += g; } else { s0b += sig; s1b += g; }
    }

    // stage per-thread 4-col pooled partials for the 4x4 pooling
    l_s0a[tid] = s0a; l_s0b[tid] = s0b; l_s1a[tid] = s1a; l_s1b[tid] = s1b;
    __syncthreads();

    // ---- fd loss: wave 0 finishes the 4x4 pooling (sum over the 4 rows) ----
    if (tid < 64) {
        const float A0 = l_s0a[tid] + l_s0a[tid+64] + l_s0a[tid+128] + l_s0a[tid+192];
        const float B0 = l_s0b[tid] + l_s0b[tid+64] + l_s0b[tid+128] + l_s0b[tid+192];
        const float A1 = l_s1a[tid] + l_s1a[tid+64] + l_s1a[tid+128] + l_s1a[tid+192];
        const float B1 = l_s1b[tid] + l_s1b[tid+64] + l_s1b[tid+128] + l_s1b[tid+192];
        const float S0a = A0 * 0.0625f, S0b = B0 * 0.0625f;
        const float S1a = A1 * 0.0625f, S1b = B1 * 0.0625f;
        const float m0a = (S0a > 0.f && S0a < 16.f) ? S0a : 0.f;
        const float m0b = (S0b > 0.f && S0b < 16.f) ? S0b : 0.f;
        const float m1a = (S1a > 0.f && S1a < 16.f) ? S1a : 0.f;
        const float m1b = (S1b > 0.f && S1b < 16.f) ? S1b : 0.f;
        float fdd = fabsf(m0a - m1a) + fabsf(m0b - m1b);
        float fdc = ((m1a > 0.f) ? 1.f : 0.f) + ((m1b > 0.f) ? 1.f : 0.f);
        fdd = wave_reduce_add(fdd);
        fdc = wave_reduce_add(fdc);
        if (tid == 0) { atomicAdd(acc + 1, fdd); atomicAdd(acc + 2, fdc); }
    }

    // ---- bce: per-wave reduce, stash in LDS ----
    {
        const float bs = wave_reduce_add(bce);
        if ((tid & 63) == 0) l_bce[tid >> 6] = bs;
    }

    // ---- patch loss: reduce within each 8-lane group (one 64-col patch column) ----
    float d8 = dsum, c8 = cnt;
    d8 += __shfl_down(d8, 4, 64); d8 += __shfl_down(d8, 2, 64); d8 += __shfl_down(d8, 1, 64);
    c8 += __shfl_down(c8, 4, 64); c8 += __shfl_down(c8, 2, 64); c8 += __shfl_down(c8, 1, 64);
    if ((c & 7) == 0) {
        const int pc = c >> 3;
        l_pd[r * 8 + pc] = d8;
        l_pc[r * 8 + pc] = c8;
    }
    __syncthreads();

    if (tid == 0) {
        atomicAdd(acc + 0, l_bce[0] + l_bce[1] + l_bce[2] + l_bce[3]);
    }
    if (tid < 8) {
        const float d  = l_pd[tid] + l_pd[8 + tid] + l_pd[16 + tid] + l_pd[24 + tid];
        const float ct = l_pc[tid] + l_pc[8 + tid] + l_pc[16 + tid] + l_pc[24 + tid];
        const int prow = rg >> 4;   // row/64
        atomicAdd(acc + 3  + prow * 8 + tid, d);
        atomicAdd(acc + 67 + prow * 8 + tid, ct);
    }
}

__global__ void loss_finalize(const float* __restrict__ acc, float* __restrict__ out)
{
    if (threadIdx.x != 0 || blockIdx.x != 0) return;
    const float Nf = (float)N_IMG;

    const float bce = -acc[0] / (float)((size_t)N_IMG * H_IMG * W_IMG);

    // fd loss
    const float cfd = acc[1] / fmaxf(acc[2], EPSF);
    const float vessel = sqrtf(Nf * 512.f * cfd * cfd);
    float st2 = 0.f;
    for (int j = 9; j >= 2; --j) { const float s = exp2f((float)j); st2 += s * s; }
    const float loss_fd = vessel / sqrtf(st2) / Nf;

    // patch loss
    float total = 0.f;
    {   // ps=64: 8x8 grid
        float ts = 0.f;
        for (int i = 0; i < 64; ++i) {
            const float cc = acc[3 + i] / fmaxf(acc[67 + i], EPSF);
            ts += 64.f * Nf * cc * cc;
        }
        float local = sqrtf(ts) / 512.f / Nf;
        total += fminf(fmaxf(local, 0.f), 1.f);
    }
    {   // ps=128: 4x4 grid = 2x2 aggregation of the 8x8
        float ts = 0.f;
        for (int i = 0; i < 4; ++i) for (int j = 0; j < 4; ++j) {
            float d = 0.f, ct = 0.f;
            for (int a = 0; a < 2; ++a) for (int bq = 0; bq < 2; ++bq) {
                const int idx = (2 * i + a) * 8 + (2 * j + bq);
                d += acc[3 + idx]; ct += acc[67 + idx];
            }
            const float cc = d / fmaxf(ct, EPSF);
            ts += 128.f * Nf * cc * cc;
        }
        float local = sqrtf(ts) / 512.f / Nf;
        total += fminf(fmaxf(local, 0.f), 1.f);
    }
    {   // ps=256: 2x2 grid = 4x4 aggregation of the 8x8
        float ts = 0.f;
        for (int i = 0; i < 2; ++i) for (int j = 0; j < 2; ++j) {
            float d = 0.f, ct = 0.f;
            for (int a = 0; a < 4; ++a) for (int bq = 0; bq < 4; ++bq) {
                const int idx = (4 * i + a) * 8 + (4 * j + bq);
                d += acc[3 + idx]; ct += acc[67 + idx];
            }
            const float cc = d / fmaxf(ct, EPSF);
            ts += 256.f * Nf * cc * cc;
        }
        float local = sqrtf(ts) / 512.f / Nf;
        total += fminf(fmaxf(local, 0.f), 1.f);
    }
    const float loss_patch = total / 64.f;  // num_patches_last = (512/64)^2

    out[0] = 1.1f * bce + 0.02f * loss_fd + 0.03f * loss_patch;
}

extern "C" void kernel_launch(void* const* d_in, const int* in_sizes, int n_in,
                              void* d_out, int out_size, void* d_ws, size_t ws_size,
                              hipStream_t stream)
{
    const float* pred = (const float*)d_in[0];
    const float* gt   = (const float*)d_in[1];
    float* acc = (float*)d_ws;
    float* out = (float*)d_out;

    hipMemsetAsync(acc, 0, ACC_FLOATS * sizeof(float), stream);
    loss_main<<<N_IMG * (H_IMG / 4), 256, 0, stream>>>(pred, gt, acc);
    loss_finalize<<<1, 64, 0, stream>>>(acc, out);
}

// Round 2
// 40.863 us; speedup vs baseline: 9.1233x; 9.1233x over previous
//
#include <hip/hip_runtime.h>
#include <math.h>

#define N_IMG 64
#define H_IMG 512
#define W_IMG 512
#define EPSF 1e-6f

#define SLABS 16           // slabs per image, 32 rows each
#define NBLK (N_IMG * SLABS)   // 1024 main blocks
#define WSSTRIDE 20        // floats per block slot
// slot layout: [0]=bce, [1]=fd_diff, [2]=fd_cnt, [3..10]=patch_d[8], [11..18]=patch_cnt[8]

__device__ __forceinline__ float wave_reduce_add(float v) {
#pragma unroll
    for (int off = 32; off > 0; off >>= 1)
        v += __shfl_down(v, off, 64);
    return v;  // valid in lane 0
}

__global__ __launch_bounds__(256) void loss_main(
    const float* __restrict__ pred, const float* __restrict__ gt,
    float* __restrict__ ws)
{
    __shared__ float l_pd[4][8], l_pc[4][8], l_s[4][3];

    const int b    = blockIdx.x;
    const int n    = b >> 4;          // image
    const int slab = b & 15;          // 32-row slab
    const int tid  = threadIdx.x;
    const int w    = tid >> 6;        // wave 0..3
    const int lane = tid & 63;
    const int r4   = tid >> 5;        // 0..7 : 4-row group within slab
    const int c    = tid & 31;        // 0..31 : col lane

    float s0[4] = {0,0,0,0}, s1[4] = {0,0,0,0};   // fd pool-cell sums (sig, gt)
    float pd[4] = {0,0,0,0}, pc[4] = {0,0,0,0};   // patch dsum / cnt per k
    float bce = 0.f;

    const int row0 = slab * 32 + r4 * 4;
#pragma unroll
    for (int rr = 0; rr < 4; ++rr) {
        const size_t rowbase = ((size_t)(n * H_IMG + row0 + rr)) * W_IMG;
#pragma unroll
        for (int k = 0; k < 4; ++k) {
            // lane c's k-th float4 at col c*4 + k*128: contiguous across lanes
            const size_t off = rowbase + (size_t)(c * 4 + k * 128);
            const float4 p4 = *(const float4*)(pred + off);
            const float4 g4 = *(const float4*)(gt + off);
            const float pv[4] = {p4.x, p4.y, p4.z, p4.w};
            const float gv[4] = {g4.x, g4.y, g4.z, g4.w};
#pragma unroll
            for (int i = 0; i < 4; ++i) {
                const float p = pv[i], g = gv[i];
                const float sig = __builtin_amdgcn_rcpf(1.0f + __expf(-p));
                // gt is exactly 0/1: g*log(p)+(1-g)*log(1-p) == log(g>0.5 ? p : 1-p)
                bce   += __logf(g > 0.5f ? p : 1.0f - p);
                pd[k] += fabsf(sig - g);
                pc[k] += (g > 0.f) ? 1.f : 0.f;
                s0[k] += sig;
                s1[k] += g;
            }
        }
    }

    // ---- fd loss: each (thread,k) is exactly one 4x4 pool cell ----
    float fdd = 0.f, fdc = 0.f;
#pragma unroll
    for (int k = 0; k < 4; ++k) {
        const float m0r = s0[k] * 0.0625f, m1r = s1[k] * 0.0625f;
        const float m0 = (m0r > 0.f && m0r < 16.f) ? m0r : 0.f;
        const float m1 = (m1r > 0.f && m1r < 16.f) ? m1r : 0.f;
        fdd += fabsf(m0 - m1);
        fdc += (m1 > 0.f) ? 1.f : 0.f;
    }

    // ---- block-wide reduce of bce, fdd, fdc ----
    {
        const float b0 = wave_reduce_add(bce);
        const float b1 = wave_reduce_add(fdd);
        const float b2 = wave_reduce_add(fdc);
        if (lane == 0) { l_s[w][0] = b0; l_s[w][1] = b1; l_s[w][2] = b2; }
    }

    // ---- patch columns: k-th float4 lies in pcol = 2k + (c>>4) ----
#pragma unroll
    for (int k = 0; k < 4; ++k) {
        float d = pd[k], ct = pc[k];
        d  += __shfl_down(d, 32, 64);  ct += __shfl_down(ct, 32, 64);
        d  += __shfl_down(d,  8, 64);  ct += __shfl_down(ct,  8, 64);
        d  += __shfl_down(d,  4, 64);  ct += __shfl_down(ct,  4, 64);
        d  += __shfl_down(d,  2, 64);  ct += __shfl_down(ct,  2, 64);
        d  += __shfl_down(d,  1, 64);  ct += __shfl_down(ct,  1, 64);
        if (lane == 0 || lane == 16) {
            const int pcol = 2 * k + (lane >> 4);
            l_pd[w][pcol] = d;
            l_pc[w][pcol] = ct;
        }
    }
    __syncthreads();

    float* slot = ws + (size_t)b * WSSTRIDE;
    if (tid == 0) {
        slot[0] = l_s[0][0] + l_s[1][0] + l_s[2][0] + l_s[3][0];
        slot[1] = l_s[0][1] + l_s[1][1] + l_s[2][1] + l_s[3][1];
        slot[2] = l_s[0][2] + l_s[1][2] + l_s[2][2] + l_s[3][2];
    }
    if (tid < 8) {
        slot[3  + tid] = l_pd[0][tid] + l_pd[1][tid] + l_pd[2][tid] + l_pd[3][tid];
        slot[11 + tid] = l_pc[0][tid] + l_pc[1][tid] + l_pc[2][tid] + l_pc[3][tid];
    }
}

__global__ __launch_bounds__(256) void loss_finalize(
    const float* __restrict__ ws, float* __restrict__ out)
{
    __shared__ float l_a[12];          // per-wave bce/fdd/fdc
    __shared__ float l_cell[64][2];    // 8x8 patch grid: [cell][0]=dsum, [1]=cnt
    const int tid = threadIdx.x;

    // Phase A: bce / fd sums over all 1024 block slots
    float a0 = 0.f, a1 = 0.f, a2 = 0.f;
    for (int b = tid; b < NBLK; b += 256) {
        const float* p = ws + (size_t)b * WSSTRIDE;
        a0 += p[0]; a1 += p[1]; a2 += p[2];
    }
    a0 = wave_reduce_add(a0);
    a1 = wave_reduce_add(a1);
    a2 = wave_reduce_add(a2);
    if ((tid & 63) == 0) {
        const int w = tid >> 6;
        l_a[w * 3 + 0] = a0; l_a[w * 3 + 1] = a1; l_a[w * 3 + 2] = a2;
    }

    // Phase B: 64 patch cells; cell = prow*8+pcol, blocks b = n*16 + prow*2 + sl
    if (tid < 128) {
        const int cell = tid >> 1, sel = tid & 1;
        const int prow = cell >> 3, pcol = cell & 7;
        const int ofs = (sel ? 11 : 3) + pcol;
        float s = 0.f;
#pragma unroll 4
        for (int n = 0; n < N_IMG; ++n) {
            const int bb = n * SLABS + prow * 2;
            s += ws[(size_t)bb * WSSTRIDE + ofs] + ws[(size_t)(bb + 1) * WSSTRIDE + ofs];
        }
        l_cell[cell][sel] = s;
    }
    __syncthreads();

    if (tid != 0) return;

    const float Nf = (float)N_IMG;
    const float bce_sum = l_a[0] + l_a[3] + l_a[6] + l_a[9];
    const float fd_d    = l_a[1] + l_a[4] + l_a[7] + l_a[10];
    const float fd_c    = l_a[2] + l_a[5] + l_a[8] + l_a[11];

    const float bce = -bce_sum / (float)((size_t)N_IMG * H_IMG * W_IMG);

    // fd loss
    const float cfd = fd_d / fmaxf(fd_c, EPSF);
    const float vessel = sqrtf(Nf * 512.f * cfd * cfd);
    float st2 = 0.f;
    for (int j = 9; j >= 2; --j) { const float s = exp2f((float)j); st2 += s * s; }
    const float loss_fd = vessel / sqrtf(st2) / Nf;

    // patch loss
    float total = 0.f;
    {   // ps=64: 8x8 grid
        float ts = 0.f;
        for (int i = 0; i < 64; ++i) {
            const float cc = l_cell[i][0] / fmaxf(l_cell[i][1], EPSF);
            ts += 64.f * Nf * cc * cc;
        }
        float local = sqrtf(ts) / 512.f / Nf;
        total += fminf(fmaxf(local, 0.f), 1.f);
    }
    {   // ps=128: 2x2 aggregation of the 8x8
        float ts = 0.f;
        for (int i = 0; i < 4; ++i) for (int j = 0; j < 4; ++j) {
            float d = 0.f, ct = 0.f;
            for (int a = 0; a < 2; ++a) for (int bq = 0; bq < 2; ++bq) {
                const int idx = (2 * i + a) * 8 + (2 * j + bq);
                d += l_cell[idx][0]; ct += l_cell[idx][1];
            }
            const float cc = d / fmaxf(ct, EPSF);
            ts += 128.f * Nf * cc * cc;
        }
        float local = sqrtf(ts) / 512.f / Nf;
        total += fminf(fmaxf(local, 0.f), 1.f);
    }
    {   // ps=256: 4x4 aggregation of the 8x8
        float ts = 0.f;
        for (int i = 0; i < 2; ++i) for (int j = 0; j < 2; ++j) {
            float d = 0.f, ct = 0.f;
            for (int a = 0; a < 4; ++a) for (int bq = 0; bq < 4; ++bq) {
                const int idx = (4 * i + a) * 8 + (4 * j + bq);
                d += l_cell[idx][0]; ct += l_cell[idx][1];
            }
            const float cc = d / fmaxf(ct, EPSF);
            ts += 256.f * Nf * cc * cc;
        }
        float local = sqrtf(ts) / 512.f / Nf;
        total += fminf(fmaxf(local, 0.f), 1.f);
    }
    const float loss_patch = total / 64.f;  // (512/64)^2

    out[0] = 1.1f * bce + 0.02f * loss_fd + 0.03f * loss_patch;
}

extern "C" void kernel_launch(void* const* d_in, const int* in_sizes, int n_in,
                              void* d_out, int out_size, void* d_ws, size_t ws_size,
                              hipStream_t stream)
{
    const float* pred = (const float*)d_in[0];
    const float* gt   = (const float*)d_in[1];
    float* ws  = (float*)d_ws;
    float* out = (float*)d_out;

    // every ws slot is fully written by loss_main each call: no memset needed
    loss_main<<<NBLK, 256, 0, stream>>>(pred, gt, ws);
    loss_finalize<<<1, 256, 0, stream>>>(ws, out);
}